// Round 1
// baseline (5996.064 us; speedup 1.0000x reference)
//
#include <hip/hip_runtime.h>
#include <math.h>

#define HEADS   16
#define HEAD_DIM 88
#define DPAD    96
#define SEQ     577
#define HIDDEN  1408
#define NQKV    4224
#define RD      44
#define SCALE_F 0.1066003581778052f  // 88^-0.5

// ---------------------------------------------------------------- rope table
__global__ void rope_precompute(float* __restrict__ cosb, float* __restrict__ sinb) {
    int s = blockIdx.x;
    int j = threadIdx.x;
    if (j >= RD) return;
    float c, sn;
    if (s == SEQ - 1) {
        c = 1.f; sn = 0.f;   // idx = -2 -> freqs masked to 0
    } else {
        int fx = s % 24, fy = s / 24;
        int p = (j < 22) ? j : j - 22;
        float inv = powf(10000.f, -(float)p / 22.f);   // base^(-(2p)/44)
        float f = (float)((j < 22 ? fx : fy) + 1) * inv;
        c = cosf(f); sn = sinf(f);
    }
    cosb[s * RD + j] = c;
    sinb[s * RD + j] = sn;
}

// ------------------------------------------------- QKV GEMM + bias + RoPE
// C[M x 4224] = A[M x 1408] * W[1408 x 4224]; scatter to q/k/v [b][h][s][d]
__global__ __launch_bounds__(256) void qkv_gemm(
    const float* __restrict__ A, const float* __restrict__ Bw,
    const float* __restrict__ bias,
    const float* __restrict__ cosb, const float* __restrict__ sinb,
    float* __restrict__ qws, float* __restrict__ kws, float* __restrict__ vws,
    int Mchunk, int b_off)
{
    __shared__ float As[8][128];
    __shared__ float Bs[8][128];
    int tid = threadIdx.x;
    int n0 = blockIdx.x * 128;
    int m0 = blockIdx.y * 128;
    int tr = tid >> 4;       // 0..15 -> rows tr*8..tr*8+7
    int tc = tid & 15;       // 0..15 -> cols tc*8..tc*8+7
    float acc[8][8] = {};

    int a_row = m0 + (tid >> 1);
    int a_k   = (tid & 1) * 4;
    int b_kk  = tid >> 5;
    int b_n   = (tid & 31) << 2;

    for (int k0 = 0; k0 < HIDDEN; k0 += 8) {
        float4 av = make_float4(0.f, 0.f, 0.f, 0.f);
        if (a_row < Mchunk)
            av = *(const float4*)(A + (size_t)((size_t)b_off * SEQ + a_row) * HIDDEN + k0 + a_k);
        As[a_k + 0][tid >> 1] = av.x;
        As[a_k + 1][tid >> 1] = av.y;
        As[a_k + 2][tid >> 1] = av.z;
        As[a_k + 3][tid >> 1] = av.w;
        float4 bv = *(const float4*)(Bw + (size_t)(k0 + b_kk) * NQKV + n0 + b_n);
        *(float4*)&Bs[b_kk][b_n] = bv;
        __syncthreads();
        for (int kk = 0; kk < 8; ++kk) {
            float ar[8], br[8];
            *(float4*)(ar)     = *(float4*)&As[kk][tr * 8];
            *(float4*)(ar + 4) = *(float4*)&As[kk][tr * 8 + 4];
            *(float4*)(br)     = *(float4*)&Bs[kk][tc * 8];
            *(float4*)(br + 4) = *(float4*)&Bs[kk][tc * 8 + 4];
            #pragma unroll
            for (int i = 0; i < 8; ++i)
                #pragma unroll
                for (int j = 0; j < 8; ++j)
                    acc[i][j] += ar[i] * br[j];
        }
        __syncthreads();
    }

    int col0 = n0 + tc * 8;
    int sec = col0 / HIDDEN;           // 0=q 1=k 2=v (8-col chunk never straddles)
    int scol = col0 - sec * HIDDEN;
    int h  = scol / HEAD_DIM;
    int d0 = scol % HEAD_DIM;          // even, 8-aligned
    float* dst = (sec == 0) ? qws : ((sec == 1) ? kws : vws);

    for (int i = 0; i < 8; ++i) {
        int m = m0 + tr * 8 + i;
        if (m >= Mchunk) break;
        int bb = m / SEQ, s = m - bb * SEQ;
        float v[8];
        #pragma unroll
        for (int j = 0; j < 8; ++j) v[j] = acc[i][j] + bias[col0 + j];
        if (sec < 2) {
            #pragma unroll
            for (int t = 0; t < 4; ++t) {
                int p = (d0 >> 1) + t;
                float c = cosb[s * RD + p], sn = sinb[s * RD + p];
                float x0 = v[2 * t], x1 = v[2 * t + 1];
                v[2 * t]     = x0 * c - x1 * sn;
                v[2 * t + 1] = x0 * sn + x1 * c;
            }
        }
        size_t base = ((size_t)(bb * HEADS + h) * SEQ + s) * HEAD_DIM + d0;
        *(float4*)&dst[base]     = make_float4(v[0], v[1], v[2], v[3]);
        *(float4*)&dst[base + 4] = make_float4(v[4], v[5], v[6], v[7]);
    }
}

// ------------------------------------------------------- flash attention
#define QT 64
#define KT 48
#define LSTR 100

__global__ __launch_bounds__(256) void attn_kernel(
    const float* __restrict__ qws, const float* __restrict__ kws,
    const float* __restrict__ vws, float* __restrict__ aws)
{
    __shared__ float Qs[QT][LSTR];
    __shared__ float Ks[KT][LSTR];   // reused for V
    __shared__ float Ps[QT][KT + 1];

    int tid = threadIdx.x;
    int q0 = blockIdx.x * QT;
    int h  = blockIdx.y;
    int bb = blockIdx.z;
    size_t hb = (size_t)(bb * HEADS + h) * SEQ * HEAD_DIM;
    const float* qbase = qws + hb;
    const float* kbase = kws + hb;
    const float* vbase = vws + hb;

    // load Q tile (zero-pad rows >= SEQ and cols >= 88)
    for (int it = 0; it < 6; ++it) {
        int idx = it * 256 + tid;            // < 64*24
        int row = idx / 24, slot = idx - row * 24;
        float4 val = make_float4(0.f, 0.f, 0.f, 0.f);
        int qr = q0 + row;
        if (slot < 22 && qr < SEQ)
            val = *(const float4*)(qbase + (size_t)qr * HEAD_DIM + slot * 4);
        *(float4*)&Qs[row][slot * 4] = val;
    }

    int ty = tid >> 4, tx = tid & 15;
    int r0 = ty * 4;
    int c0 = tx * 3;
    int d0 = tx * 6;
    float m_i[4], l_i[4], o[4][6];
    #pragma unroll
    for (int i = 0; i < 4; ++i) {
        m_i[i] = -INFINITY; l_i[i] = 0.f;
        #pragma unroll
        for (int j = 0; j < 6; ++j) o[i][j] = 0.f;
    }

    for (int k0 = 0; k0 < SEQ; k0 += KT) {
        int kv = (SEQ - k0 < KT) ? (SEQ - k0) : KT;
        // load K tile
        for (int it = 0; it < 5; ++it) {
            int idx = it * 256 + tid;
            if (idx < KT * 24) {
                int row = idx / 24, slot = idx - row * 24;
                float4 val = make_float4(0.f, 0.f, 0.f, 0.f);
                if (slot < 22 && row < kv)
                    val = *(const float4*)(kbase + (size_t)(k0 + row) * HEAD_DIM + slot * 4);
                *(float4*)&Ks[row][slot * 4] = val;
            }
        }
        __syncthreads();

        float sc[4][3] = {};
        for (int d = 0; d < DPAD; ++d) {
            float kvl[3];
            #pragma unroll
            for (int j = 0; j < 3; ++j) kvl[j] = Ks[c0 + j][d];
            #pragma unroll
            for (int i = 0; i < 4; ++i) {
                float qv = Qs[r0 + i][d];
                #pragma unroll
                for (int j = 0; j < 3; ++j) sc[i][j] += qv * kvl[j];
            }
        }

        #pragma unroll
        for (int i = 0; i < 4; ++i) {
            float tmax = -INFINITY;
            #pragma unroll
            for (int j = 0; j < 3; ++j) {
                if (c0 + j < kv) sc[i][j] *= SCALE_F; else sc[i][j] = -INFINITY;
                tmax = fmaxf(tmax, sc[i][j]);
            }
            for (int off = 8; off; off >>= 1)
                tmax = fmaxf(tmax, __shfl_xor(tmax, off, 16));
            float mnew = fmaxf(m_i[i], tmax);
            float alpha = expf(m_i[i] - mnew);
            #pragma unroll
            for (int j = 0; j < 6; ++j) o[i][j] *= alpha;
            float rsum = 0.f;
            #pragma unroll
            for (int j = 0; j < 3; ++j) {
                float p = (c0 + j < kv) ? expf(sc[i][j] - mnew) : 0.f;
                Ps[r0 + i][c0 + j] = p;
                rsum += p;
            }
            for (int off = 8; off; off >>= 1)
                rsum += __shfl_xor(rsum, off, 16);
            l_i[i] = l_i[i] * alpha + rsum;
            m_i[i] = mnew;
        }
        __syncthreads();   // P written, K reads done

        // load V tile into Ks
        for (int it = 0; it < 5; ++it) {
            int idx = it * 256 + tid;
            if (idx < KT * 24) {
                int row = idx / 24, slot = idx - row * 24;
                float4 val = make_float4(0.f, 0.f, 0.f, 0.f);
                if (slot < 22 && row < kv)
                    val = *(const float4*)(vbase + (size_t)(k0 + row) * HEAD_DIM + slot * 4);
                *(float4*)&Ks[row][slot * 4] = val;
            }
        }
        __syncthreads();

        for (int c = 0; c < kv; ++c) {
            float vv[6];
            #pragma unroll
            for (int j = 0; j < 6; ++j) vv[j] = Ks[c][d0 + j];
            #pragma unroll
            for (int i = 0; i < 4; ++i) {
                float pp = Ps[r0 + i][c];
                #pragma unroll
                for (int j = 0; j < 6; ++j) o[i][j] += pp * vv[j];
            }
        }
        __syncthreads();   // V reads done before next K load
    }

    #pragma unroll
    for (int i = 0; i < 4; ++i) {
        int q = q0 + r0 + i;
        if (q >= SEQ) continue;
        float il = 1.f / l_i[i];
        #pragma unroll
        for (int j = 0; j < 6; ++j) {
            int d = d0 + j;
            if (d < HEAD_DIM)
                aws[(size_t)(bb * SEQ + q) * HIDDEN + h * HEAD_DIM + d] = o[i][j] * il;
        }
    }
}

// ------------------------------------------------------- out proj GEMM + bias
__global__ __launch_bounds__(256) void out_gemm(
    const float* __restrict__ A, const float* __restrict__ Bw,
    const float* __restrict__ bias, float* __restrict__ out,
    int Mchunk, int b_off)
{
    __shared__ float As[8][128];
    __shared__ float Bs[8][128];
    int tid = threadIdx.x;
    int n0 = blockIdx.x * 128;
    int m0 = blockIdx.y * 128;
    int tr = tid >> 4;
    int tc = tid & 15;
    float acc[8][8] = {};

    int a_row = m0 + (tid >> 1);
    int a_k   = (tid & 1) * 4;
    int b_kk  = tid >> 5;
    int b_n   = (tid & 31) << 2;

    for (int k0 = 0; k0 < HIDDEN; k0 += 8) {
        float4 av = make_float4(0.f, 0.f, 0.f, 0.f);
        if (a_row < Mchunk)
            av = *(const float4*)(A + (size_t)a_row * HIDDEN + k0 + a_k);
        As[a_k + 0][tid >> 1] = av.x;
        As[a_k + 1][tid >> 1] = av.y;
        As[a_k + 2][tid >> 1] = av.z;
        As[a_k + 3][tid >> 1] = av.w;
        float4 bv = *(const float4*)(Bw + (size_t)(k0 + b_kk) * HIDDEN + n0 + b_n);
        *(float4*)&Bs[b_kk][b_n] = bv;
        __syncthreads();
        for (int kk = 0; kk < 8; ++kk) {
            float ar[8], br[8];
            *(float4*)(ar)     = *(float4*)&As[kk][tr * 8];
            *(float4*)(ar + 4) = *(float4*)&As[kk][tr * 8 + 4];
            *(float4*)(br)     = *(float4*)&Bs[kk][tc * 8];
            *(float4*)(br + 4) = *(float4*)&Bs[kk][tc * 8 + 4];
            #pragma unroll
            for (int i = 0; i < 8; ++i)
                #pragma unroll
                for (int j = 0; j < 8; ++j)
                    acc[i][j] += ar[i] * br[j];
        }
        __syncthreads();
    }

    int col0 = n0 + tc * 8;
    for (int i = 0; i < 8; ++i) {
        int m = m0 + tr * 8 + i;
        if (m >= Mchunk) break;
        float v[8];
        #pragma unroll
        for (int j = 0; j < 8; ++j) v[j] = acc[i][j] + bias[col0 + j];
        size_t base = (size_t)((size_t)b_off * SEQ + m) * HIDDEN + col0;
        *(float4*)&out[base]     = make_float4(v[0], v[1], v[2], v[3]);
        *(float4*)&out[base + 4] = make_float4(v[4], v[5], v[6], v[7]);
    }
}

// ---------------------------------------------------------------- launcher
extern "C" void kernel_launch(void* const* d_in, const int* in_sizes, int n_in,
                              void* d_out, int out_size, void* d_ws, size_t ws_size,
                              hipStream_t stream) {
    const float* hs    = (const float*)d_in[0];
    const float* w_qkv = (const float*)d_in[1];
    const float* b_qkv = (const float*)d_in[2];
    const float* w_o   = (const float*)d_in[3];
    const float* b_o   = (const float*)d_in[4];
    float* out = (float*)d_out;
    float* ws  = (float*)d_ws;

    float* cosb = ws;
    float* sinb = cosb + SEQ * RD;
    float* chunkbase = sinb + SEQ * RD;

    size_t avail = ws_size / sizeof(float);
    size_t hdr = 2 * SEQ * RD;
    size_t per_batch = 4ull * SEQ * HIDDEN;   // q + k + v + attn (floats)
    int CB = 1;
    if (avail > hdr) {
        size_t c = (avail - hdr) / per_batch;
        CB = (c > 32) ? 32 : (int)c;
        if (CB < 1) CB = 1;
    }

    rope_precompute<<<dim3(SEQ), dim3(64), 0, stream>>>(cosb, sinb);

    for (int b_off = 0; b_off < 32; b_off += CB) {
        int nb = (32 - b_off < CB) ? (32 - b_off) : CB;
        int M = nb * SEQ;
        size_t sz = (size_t)nb * SEQ * HIDDEN;
        float* qws = chunkbase;
        float* kws = qws + sz;
        float* vws = kws + sz;
        float* aws = vws + sz;

        dim3 g1(NQKV / 128, (M + 127) / 128);
        qkv_gemm<<<g1, 256, 0, stream>>>(hs, w_qkv, b_qkv, cosb, sinb,
                                         qws, kws, vws, M, b_off);
        dim3 g2((SEQ + QT - 1) / QT, HEADS, nb);
        attn_kernel<<<g2, 256, 0, stream>>>(qws, kws, vws, aws);
        dim3 g3(HIDDEN / 128, (M + 127) / 128);
        out_gemm<<<g3, 256, 0, stream>>>(aws, w_o, b_o, out, M, b_off);
    }
}

// Round 2
// 2472.331 us; speedup vs baseline: 2.4253x; 2.4253x over previous
//
#include <hip/hip_runtime.h>
#include <math.h>

#define HEADS   16
#define HEAD_DIM 88
#define DPAD    96
#define SEQ     577
#define HIDDEN  1408
#define NQKV    4224
#define RD      44
#define SCALE_F 0.1066003581778052f  // 88^-0.5
#define MPAD_ROWS 18592              // 32*577=18464 rounded up +128

typedef __attribute__((ext_vector_type(8))) short bf16x8;
typedef __attribute__((ext_vector_type(4))) float f32x4;

__device__ __forceinline__ unsigned short f2bf(float x) {
    unsigned u = __float_as_uint(x);
    unsigned r = u + 0x7fff + ((u >> 16) & 1);
    return (unsigned short)(r >> 16);
}
__device__ __forceinline__ f32x4 fzero() {
    f32x4 z; z.x = 0.f; z.y = 0.f; z.z = 0.f; z.w = 0.f; return z;
}

// ---------------------------------------------------------------- rope table
__global__ void rope_precompute(float* __restrict__ cosb, float* __restrict__ sinb) {
    int s = blockIdx.x;
    int j = threadIdx.x;
    if (j >= RD) return;
    float c, sn;
    if (s == SEQ - 1) {
        c = 1.f; sn = 0.f;
    } else {
        int fx = s % 24, fy = s / 24;
        int p = (j < 22) ? j : j - 22;
        float inv = powf(10000.f, -(float)p / 22.f);
        float f = (float)((j < 22 ? fx : fy) + 1) * inv;
        c = cosf(f); sn = sinf(f);
    }
    cosb[s * RD + j] = c;
    sinb[s * RD + j] = sn;
}

// --------------------------------------------------------- fp32 -> bf16 copy
__global__ void conv_hs(const float* __restrict__ in, unsigned short* __restrict__ out,
                        long nreal, long ntot) {
    long i = ((long)blockIdx.x * 256 + threadIdx.x) * 4;
    if (i >= ntot) return;
    ushort4 o;
    if (i < nreal) {
        float4 v = *(const float4*)(in + i);
        o = make_ushort4(f2bf(v.x), f2bf(v.y), f2bf(v.z), f2bf(v.w));
    } else {
        o = make_ushort4(0, 0, 0, 0);
    }
    *(ushort4*)(out + i) = o;
}

// ------------------------------------------- fp32 [R][C] -> bf16 [C][R]
__global__ void conv_wT(const float* __restrict__ in, unsigned short* __restrict__ out,
                        int R, int C) {
    __shared__ float t[32][33];
    int bx = blockIdx.x * 32, by = blockIdx.y * 32;
    int tx = threadIdx.x & 31, ty = threadIdx.x >> 5;   // ty 0..7
    #pragma unroll
    for (int i = 0; i < 4; ++i)
        t[ty + i * 8][tx] = in[(size_t)(by + ty + i * 8) * C + bx + tx];
    __syncthreads();
    #pragma unroll
    for (int i = 0; i < 4; ++i)
        out[(size_t)(bx + ty + i * 8) * R + by + tx] = f2bf(t[tx][ty + i * 8]);
}

// -------------------------------------------------- tile staging (128x32 bf16)
// LDS slot (row r, chunk cs) holds global chunk cs ^ ((r>>1)&3); 16B per lane.
__device__ __forceinline__ void stage_tile(const unsigned short* __restrict__ src,
                                           unsigned short* lds, int tid) {
    int lane = tid & 63, w = tid >> 6;
    #pragma unroll
    for (int q = 0; q < 2; ++q) {
        int cf = lane + 64 * (q + 2 * w);   // 0..511 chunk id
        int r  = cf >> 2, cs = cf & 3;
        int cg = cs ^ ((r >> 1) & 3);
        const unsigned short* g = src + (size_t)r * HIDDEN + cg * 8;
        __builtin_amdgcn_global_load_lds(
            (const __attribute__((address_space(1))) void*)g,
            (__attribute__((address_space(3))) void*)(lds + (q + 2 * w) * 512),
            16, 0, 0);
    }
}

// ---------------------------------------------- QKV: Ct[n][m] = W_t * hs^T
__global__ __launch_bounds__(256) void qkv_mfma(
    const unsigned short* __restrict__ hsb, const unsigned short* __restrict__ wt,
    const float* __restrict__ bias, const float* __restrict__ cosb,
    const float* __restrict__ sinb,
    float* __restrict__ qws, float* __restrict__ kws, float* __restrict__ vws,
    int Mchunk, int row_off)
{
    __shared__ unsigned short Ws[128 * 32];
    __shared__ unsigned short Hs[128 * 32];
    int tid = threadIdx.x;
    int lane = tid & 63, wv = tid >> 6;
    int quad = lane >> 4, l15 = lane & 15;
    int wn = wv & 1, wm = wv >> 1;
    int n0 = blockIdx.x * 128;
    int m0 = blockIdx.y * 128;

    f32x4 acc[4][4];
    #pragma unroll
    for (int i = 0; i < 4; ++i)
        #pragma unroll
        for (int j = 0; j < 4; ++j) acc[i][j] = fzero();

    const unsigned short* wsrc = wt  + (size_t)n0 * HIDDEN;
    const unsigned short* hsrc = hsb + (size_t)(row_off + m0) * HIDDEN;

    for (int k0 = 0; k0 < HIDDEN; k0 += 32) {
        stage_tile(wsrc + k0, Ws, tid);
        stage_tile(hsrc + k0, Hs, tid);
        __syncthreads();
        bf16x8 af[4], bfr[4];
        #pragma unroll
        for (int i = 0; i < 4; ++i) {
            int r = wn * 64 + i * 16 + l15;
            af[i] = *(const bf16x8*)(Ws + r * 32 + ((quad ^ ((r >> 1) & 3)) << 3));
        }
        #pragma unroll
        for (int j = 0; j < 4; ++j) {
            int r = wm * 64 + j * 16 + l15;
            bfr[j] = *(const bf16x8*)(Hs + r * 32 + ((quad ^ ((r >> 1) & 3)) << 3));
        }
        #pragma unroll
        for (int i = 0; i < 4; ++i)
            #pragma unroll
            for (int j = 0; j < 4; ++j)
                acc[i][j] = __builtin_amdgcn_mfma_f32_16x16x32_bf16(
                    af[i], bfr[j], acc[i][j], 0, 0, 0);
        __syncthreads();
    }

    // epilogue: D rows = qkv-col n (quad*4+reg), D cols = token m (l15)
    int sec   = n0 / HIDDEN;                 // 128 | 1408 -> uniform per block
    int nsec0 = n0 - sec * HIDDEN;
    float* dst = (sec == 0) ? qws : ((sec == 1) ? kws : vws);
    #pragma unroll
    for (int j = 0; j < 4; ++j) {
        int m = m0 + wm * 64 + j * 16 + l15;
        if (m >= Mchunk) continue;
        int bb = m / SEQ;
        int s  = m - bb * SEQ;
        const float* cr = cosb + s * RD;
        const float* sr = sinb + s * RD;
        #pragma unroll
        for (int i = 0; i < 4; ++i) {
            int nn = nsec0 + wn * 64 + i * 16 + quad * 4;
            int h  = nn / HEAD_DIM;
            int d0 = nn - h * HEAD_DIM;      // multiple of 4, never straddles head
            f32x4 v = acc[i][j];
            const float4 bv = *(const float4*)(bias + sec * HIDDEN + nn);
            v.x += bv.x; v.y += bv.y; v.z += bv.z; v.w += bv.w;
            if (sec < 2) {
                int p0 = d0 >> 1;
                float c0 = cr[p0],     s0 = sr[p0];
                float c1 = cr[p0 + 1], s1 = sr[p0 + 1];
                float x0 = v.x, x1 = v.y;
                v.x = x0 * c0 - x1 * s0; v.y = x0 * s0 + x1 * c0;
                x0 = v.z; x1 = v.w;
                v.z = x0 * c1 - x1 * s1; v.w = x0 * s1 + x1 * c1;
            }
            *(f32x4*)(dst + ((size_t)(bb * HEADS + h) * SEQ + s) * HEAD_DIM + d0) = v;
        }
    }
}

// ---------------------------------------------- out proj: out = attn @ W_o + b
__global__ __launch_bounds__(256) void out_mfma(
    const unsigned short* __restrict__ ab, const unsigned short* __restrict__ wt,
    const float* __restrict__ bias, float* __restrict__ out,
    int Mchunk, int row_off)
{
    __shared__ unsigned short Ws[128 * 32];
    __shared__ unsigned short Hs[128 * 32];
    int tid = threadIdx.x;
    int lane = tid & 63, wv = tid >> 6;
    int quad = lane >> 4, l15 = lane & 15;
    int wn = wv & 1, wm = wv >> 1;
    int n0 = blockIdx.x * 128;
    int m0 = blockIdx.y * 128;

    f32x4 acc[4][4];
    #pragma unroll
    for (int i = 0; i < 4; ++i)
        #pragma unroll
        for (int j = 0; j < 4; ++j) acc[i][j] = fzero();

    const unsigned short* wsrc = wt + (size_t)n0 * HIDDEN;
    const unsigned short* asrc = ab + (size_t)m0 * HIDDEN;

    for (int k0 = 0; k0 < HIDDEN; k0 += 32) {
        stage_tile(wsrc + k0, Ws, tid);
        stage_tile(asrc + k0, Hs, tid);
        __syncthreads();
        bf16x8 af[4], bfr[4];
        #pragma unroll
        for (int i = 0; i < 4; ++i) {
            int r = wn * 64 + i * 16 + l15;
            af[i] = *(const bf16x8*)(Ws + r * 32 + ((quad ^ ((r >> 1) & 3)) << 3));
        }
        #pragma unroll
        for (int j = 0; j < 4; ++j) {
            int r = wm * 64 + j * 16 + l15;
            bfr[j] = *(const bf16x8*)(Hs + r * 32 + ((quad ^ ((r >> 1) & 3)) << 3));
        }
        #pragma unroll
        for (int i = 0; i < 4; ++i)
            #pragma unroll
            for (int j = 0; j < 4; ++j)
                acc[i][j] = __builtin_amdgcn_mfma_f32_16x16x32_bf16(
                    af[i], bfr[j], acc[i][j], 0, 0, 0);
        __syncthreads();
    }

    #pragma unroll
    for (int j = 0; j < 4; ++j) {
        int m = m0 + wm * 64 + j * 16 + l15;
        if (m >= Mchunk) continue;
        size_t orow = (size_t)(row_off + m) * HIDDEN;
        #pragma unroll
        for (int i = 0; i < 4; ++i) {
            int nn = n0 + wn * 64 + i * 16 + quad * 4;
            f32x4 v = acc[i][j];
            const float4 bv = *(const float4*)(bias + nn);
            v.x += bv.x; v.y += bv.y; v.z += bv.z; v.w += bv.w;
            *(f32x4*)(out + orow + nn) = v;
        }
    }
}

// ------------------------------------------------------- flash attention (fp32)
#define QT 64
#define KT 48
#define LSTR 100

__global__ __launch_bounds__(256) void attn_kernel(
    const float* __restrict__ qws, const float* __restrict__ kws,
    const float* __restrict__ vws, unsigned short* __restrict__ awsb)
{
    __shared__ float Qs[QT][LSTR];
    __shared__ float Ks[KT][LSTR];
    __shared__ float Ps[QT][KT + 1];

    int tid = threadIdx.x;
    int q0 = blockIdx.x * QT;
    int h  = blockIdx.y;
    int bb = blockIdx.z;
    size_t hb = (size_t)(bb * HEADS + h) * SEQ * HEAD_DIM;
    const float* qbase = qws + hb;
    const float* kbase = kws + hb;
    const float* vbase = vws + hb;

    for (int it = 0; it < 6; ++it) {
        int idx = it * 256 + tid;
        int row = idx / 24, slot = idx - row * 24;
        float4 val = make_float4(0.f, 0.f, 0.f, 0.f);
        int qr = q0 + row;
        if (slot < 22 && qr < SEQ)
            val = *(const float4*)(qbase + (size_t)qr * HEAD_DIM + slot * 4);
        *(float4*)&Qs[row][slot * 4] = val;
    }

    int ty = tid >> 4, tx = tid & 15;
    int r0 = ty * 4;
    int c0 = tx * 3;
    int d0 = tx * 6;
    float m_i[4], l_i[4], o[4][6];
    #pragma unroll
    for (int i = 0; i < 4; ++i) {
        m_i[i] = -INFINITY; l_i[i] = 0.f;
        #pragma unroll
        for (int j = 0; j < 6; ++j) o[i][j] = 0.f;
    }

    for (int k0 = 0; k0 < SEQ; k0 += KT) {
        int kv = (SEQ - k0 < KT) ? (SEQ - k0) : KT;
        for (int it = 0; it < 5; ++it) {
            int idx = it * 256 + tid;
            if (idx < KT * 24) {
                int row = idx / 24, slot = idx - row * 24;
                float4 val = make_float4(0.f, 0.f, 0.f, 0.f);
                if (slot < 22 && row < kv)
                    val = *(const float4*)(kbase + (size_t)(k0 + row) * HEAD_DIM + slot * 4);
                *(float4*)&Ks[row][slot * 4] = val;
            }
        }
        __syncthreads();

        float sc[4][3] = {};
        for (int d = 0; d < DPAD; ++d) {
            float kvl[3];
            #pragma unroll
            for (int j = 0; j < 3; ++j) kvl[j] = Ks[c0 + j][d];
            #pragma unroll
            for (int i = 0; i < 4; ++i) {
                float qv = Qs[r0 + i][d];
                #pragma unroll
                for (int j = 0; j < 3; ++j) sc[i][j] += qv * kvl[j];
            }
        }

        #pragma unroll
        for (int i = 0; i < 4; ++i) {
            float tmax = -INFINITY;
            #pragma unroll
            for (int j = 0; j < 3; ++j) {
                if (c0 + j < kv) sc[i][j] *= SCALE_F; else sc[i][j] = -INFINITY;
                tmax = fmaxf(tmax, sc[i][j]);
            }
            for (int off = 8; off; off >>= 1)
                tmax = fmaxf(tmax, __shfl_xor(tmax, off, 16));
            float mnew = fmaxf(m_i[i], tmax);
            float alpha = expf(m_i[i] - mnew);
            #pragma unroll
            for (int j = 0; j < 6; ++j) o[i][j] *= alpha;
            float rsum = 0.f;
            #pragma unroll
            for (int j = 0; j < 3; ++j) {
                float p = (c0 + j < kv) ? expf(sc[i][j] - mnew) : 0.f;
                Ps[r0 + i][c0 + j] = p;
                rsum += p;
            }
            for (int off = 8; off; off >>= 1)
                rsum += __shfl_xor(rsum, off, 16);
            l_i[i] = l_i[i] * alpha + rsum;
            m_i[i] = mnew;
        }
        __syncthreads();

        for (int it = 0; it < 5; ++it) {
            int idx = it * 256 + tid;
            if (idx < KT * 24) {
                int row = idx / 24, slot = idx - row * 24;
                float4 val = make_float4(0.f, 0.f, 0.f, 0.f);
                if (slot < 22 && row < kv)
                    val = *(const float4*)(vbase + (size_t)(k0 + row) * HEAD_DIM + slot * 4);
                *(float4*)&Ks[row][slot * 4] = val;
            }
        }
        __syncthreads();

        for (int c = 0; c < kv; ++c) {
            float vv[6];
            #pragma unroll
            for (int j = 0; j < 6; ++j) vv[j] = Ks[c][d0 + j];
            #pragma unroll
            for (int i = 0; i < 4; ++i) {
                float pp = Ps[r0 + i][c];
                #pragma unroll
                for (int j = 0; j < 6; ++j) o[i][j] += pp * vv[j];
            }
        }
        __syncthreads();
    }

    #pragma unroll
    for (int i = 0; i < 4; ++i) {
        int q = q0 + r0 + i;
        if (q >= SEQ) continue;
        float il = 1.f / l_i[i];
        #pragma unroll
        for (int j = 0; j < 6; ++j) {
            int d = d0 + j;
            if (d < HEAD_DIM)
                awsb[(size_t)(bb * SEQ + q) * HIDDEN + h * HEAD_DIM + d] =
                    f2bf(o[i][j] * il);
        }
    }
}

// ---------------------------------------------------------------- launcher
extern "C" void kernel_launch(void* const* d_in, const int* in_sizes, int n_in,
                              void* d_out, int out_size, void* d_ws, size_t ws_size,
                              hipStream_t stream) {
    const float* hs    = (const float*)d_in[0];
    const float* w_qkv = (const float*)d_in[1];
    const float* b_qkv = (const float*)d_in[2];
    const float* w_o   = (const float*)d_in[3];
    const float* b_o   = (const float*)d_in[4];
    float* out = (float*)d_out;

    char* p = (char*)d_ws;
    auto alloc = [&](size_t bytes) {
        char* r = p; p += (bytes + 255) & ~(size_t)255; return r;
    };
    float*          cosb   = (float*)alloc((size_t)SEQ * RD * 4);
    float*          sinb   = (float*)alloc((size_t)SEQ * RD * 4);
    unsigned short* wqkv_t = (unsigned short*)alloc((size_t)NQKV * HIDDEN * 2);
    unsigned short* wo_t   = (unsigned short*)alloc((size_t)HIDDEN * HIDDEN * 2);
    unsigned short* hs_bf  = (unsigned short*)alloc((size_t)MPAD_ROWS * HIDDEN * 2);
    size_t fixed = (size_t)(p - (char*)d_ws);

    size_t per_batch = 3ull * SEQ * HIDDEN * 4 + (size_t)SEQ * HIDDEN * 2;
    size_t extra = 128ull * HIDDEN * 2 + 8 * 256;     // attn pad rows + align slack
    size_t rem = (ws_size > fixed + extra) ? ws_size - fixed - extra : 0;
    int CB = (int)(rem / per_batch);
    if (CB < 1) CB = 1;
    if (CB > 32) CB = 32;

    float*          qws  = (float*)alloc((size_t)CB * SEQ * HIDDEN * 4);
    float*          kws  = (float*)alloc((size_t)CB * SEQ * HIDDEN * 4);
    float*          vws  = (float*)alloc((size_t)CB * SEQ * HIDDEN * 4);
    unsigned short* awsb = (unsigned short*)alloc(((size_t)CB * SEQ + 128) * HIDDEN * 2);

    rope_precompute<<<dim3(SEQ), dim3(64), 0, stream>>>(cosb, sinb);

    long nreal = (long)32 * SEQ * HIDDEN;
    long ntot  = (long)MPAD_ROWS * HIDDEN;
    conv_hs<<<dim3((unsigned)((ntot / 4 + 255) / 256)), 256, 0, stream>>>(hs, hs_bf, nreal, ntot);
    conv_wT<<<dim3(NQKV / 32, HIDDEN / 32), 256, 0, stream>>>(w_qkv, wqkv_t, HIDDEN, NQKV);
    conv_wT<<<dim3(HIDDEN / 32, HIDDEN / 32), 256, 0, stream>>>(w_o, wo_t, HIDDEN, HIDDEN);

    for (int b_off = 0; b_off < 32; b_off += CB) {
        int nb = (32 - b_off < CB) ? (32 - b_off) : CB;
        int M = nb * SEQ;

        dim3 g1(NQKV / 128, (M + 127) / 128);
        qkv_mfma<<<g1, 256, 0, stream>>>(hs_bf, wqkv_t, b_qkv, cosb, sinb,
                                         qws, kws, vws, M, b_off * SEQ);
        dim3 g2((SEQ + QT - 1) / QT, HEADS, nb);
        attn_kernel<<<g2, 256, 0, stream>>>(qws, kws, vws, awsb);
        dim3 g3(HIDDEN / 128, (M + 127) / 128);
        out_mfma<<<g3, 256, 0, stream>>>(awsb, wo_t, b_o, out, M, b_off * SEQ);
    }
}

// Round 3
// 888.697 us; speedup vs baseline: 6.7470x; 2.7820x over previous
//
#include <hip/hip_runtime.h>
#include <math.h>

#define HEADS   16
#define HEAD_DIM 88
#define SEQ     577
#define SEQV    640
#define HIDDEN  1408
#define NQKV    4224
#define RD      44
#define SCALE_F 0.1066003581778052f  // 88^-0.5
#define MPAD_ROWS 18592

typedef __attribute__((ext_vector_type(8))) short bf16x8;
typedef __attribute__((ext_vector_type(4))) float f32x4;

__device__ __forceinline__ unsigned short f2bf(float x) {
    unsigned u = __float_as_uint(x);
    unsigned r = u + 0x7fff + ((u >> 16) & 1);
    return (unsigned short)(r >> 16);
}
__device__ __forceinline__ f32x4 fzero() {
    f32x4 z; z.x = 0.f; z.y = 0.f; z.z = 0.f; z.w = 0.f; return z;
}

// ---------------------------------------------------------------- rope table
__global__ void rope_precompute(float* __restrict__ cosb, float* __restrict__ sinb) {
    int s = blockIdx.x;
    int j = threadIdx.x;
    if (j >= RD) return;
    float c, sn;
    if (s == SEQ - 1) {
        c = 1.f; sn = 0.f;
    } else {
        int fx = s % 24, fy = s / 24;
        int p = (j < 22) ? j : j - 22;
        float inv = powf(10000.f, -(float)p / 22.f);
        float f = (float)((j < 22 ? fx : fy) + 1) * inv;
        c = cosf(f); sn = sinf(f);
    }
    cosb[s * RD + j] = c;
    sinb[s * RD + j] = sn;
}

// --------------------------------------------------------- fp32 -> bf16 copy
__global__ void conv_hs(const float* __restrict__ in, unsigned short* __restrict__ out,
                        long nreal, long ntot) {
    long i = ((long)blockIdx.x * 256 + threadIdx.x) * 4;
    if (i >= ntot) return;
    ushort4 o;
    if (i < nreal) {
        float4 v = *(const float4*)(in + i);
        o = make_ushort4(f2bf(v.x), f2bf(v.y), f2bf(v.z), f2bf(v.w));
    } else {
        o = make_ushort4(0, 0, 0, 0);
    }
    *(ushort4*)(out + i) = o;
}

// ------------------------------------------- fp32 [R][C] -> bf16 [C][R]
__global__ void conv_wT(const float* __restrict__ in, unsigned short* __restrict__ out,
                        int R, int C) {
    __shared__ float t[32][33];
    int bx = blockIdx.x * 32, by = blockIdx.y * 32;
    int tx = threadIdx.x & 31, ty = threadIdx.x >> 5;
    #pragma unroll
    for (int i = 0; i < 4; ++i)
        t[ty + i * 8][tx] = in[(size_t)(by + ty + i * 8) * C + bx + tx];
    __syncthreads();
    #pragma unroll
    for (int i = 0; i < 4; ++i)
        out[(size_t)(bx + ty + i * 8) * R + by + tx] = f2bf(t[tx][ty + i * 8]);
}

// -------------------------------------------------- tile staging (128x32 bf16)
__device__ __forceinline__ void stage_tile(const unsigned short* __restrict__ src,
                                           unsigned short* lds, int tid) {
    int lane = tid & 63, w = tid >> 6;
    #pragma unroll
    for (int q = 0; q < 2; ++q) {
        int cf = lane + 64 * (q + 2 * w);
        int r  = cf >> 2, cs = cf & 3;
        int cg = cs ^ ((r >> 1) & 3);
        const unsigned short* g = src + (size_t)r * HIDDEN + cg * 8;
        __builtin_amdgcn_global_load_lds(
            (const __attribute__((address_space(1))) void*)g,
            (__attribute__((address_space(3))) void*)(lds + (q + 2 * w) * 512),
            16, 0, 0);
    }
}

// ---------------------------------------------- QKV: Ct[n][m] = W_t * hs^T
__global__ __launch_bounds__(256) void qkv_mfma(
    const unsigned short* __restrict__ hsb, const unsigned short* __restrict__ wt,
    const float* __restrict__ bias, const float* __restrict__ cosb,
    const float* __restrict__ sinb,
    unsigned short* __restrict__ qb, unsigned short* __restrict__ kb,
    unsigned short* __restrict__ vtb,
    int Mchunk, int row_off)
{
    __shared__ unsigned short Ws[128 * 32];
    __shared__ unsigned short Hs[128 * 32];
    int tid = threadIdx.x;
    int lane = tid & 63, wv = tid >> 6;
    int quad = lane >> 4, l15 = lane & 15;
    int wn = wv & 1, wm = wv >> 1;
    int n0 = blockIdx.x * 128;
    int m0 = blockIdx.y * 128;

    f32x4 acc[4][4];
    #pragma unroll
    for (int i = 0; i < 4; ++i)
        #pragma unroll
        for (int j = 0; j < 4; ++j) acc[i][j] = fzero();

    const unsigned short* wsrc = wt  + (size_t)n0 * HIDDEN;
    const unsigned short* hsrc = hsb + (size_t)(row_off + m0) * HIDDEN;

    for (int k0 = 0; k0 < HIDDEN; k0 += 32) {
        stage_tile(wsrc + k0, Ws, tid);
        stage_tile(hsrc + k0, Hs, tid);
        __syncthreads();
        bf16x8 af[4], bfr[4];
        #pragma unroll
        for (int i = 0; i < 4; ++i) {
            int r = wn * 64 + i * 16 + l15;
            af[i] = *(const bf16x8*)(Ws + r * 32 + ((quad ^ ((r >> 1) & 3)) << 3));
        }
        #pragma unroll
        for (int j = 0; j < 4; ++j) {
            int r = wm * 64 + j * 16 + l15;
            bfr[j] = *(const bf16x8*)(Hs + r * 32 + ((quad ^ ((r >> 1) & 3)) << 3));
        }
        #pragma unroll
        for (int i = 0; i < 4; ++i)
            #pragma unroll
            for (int j = 0; j < 4; ++j)
                acc[i][j] = __builtin_amdgcn_mfma_f32_16x16x32_bf16(
                    af[i], bfr[j], acc[i][j], 0, 0, 0);
        __syncthreads();
    }

    int sec   = n0 / HIDDEN;
    int nsec0 = n0 - sec * HIDDEN;
    #pragma unroll
    for (int j = 0; j < 4; ++j) {
        int m = m0 + wm * 64 + j * 16 + l15;
        if (m >= Mchunk) continue;
        int bb = m / SEQ;
        int s  = m - bb * SEQ;
        const float* cr = cosb + s * RD;
        const float* sr = sinb + s * RD;
        #pragma unroll
        for (int i = 0; i < 4; ++i) {
            int nn = nsec0 + wn * 64 + i * 16 + quad * 4;
            int h  = nn / HEAD_DIM;
            int d0 = nn - h * HEAD_DIM;
            int bh = bb * HEADS + h;
            f32x4 v = acc[i][j];
            const float4 bv = *(const float4*)(bias + sec * HIDDEN + nn);
            v.x += bv.x; v.y += bv.y; v.z += bv.z; v.w += bv.w;
            if (sec < 2) {
                int p0 = d0 >> 1;
                float c0 = cr[p0],     s0 = sr[p0];
                float c1 = cr[p0 + 1], s1 = sr[p0 + 1];
                float x0 = v.x, x1 = v.y;
                v.x = x0 * c0 - x1 * s0; v.y = x0 * s0 + x1 * c0;
                x0 = v.z; x1 = v.w;
                v.z = x0 * c1 - x1 * s1; v.w = x0 * s1 + x1 * c1;
                if (sec == 0) { v.x *= SCALE_F; v.y *= SCALE_F; v.z *= SCALE_F; v.w *= SCALE_F; }
                unsigned short* dst = (sec == 0) ? qb : kb;
                ushort4 o = make_ushort4(f2bf(v.x), f2bf(v.y), f2bf(v.z), f2bf(v.w));
                *(ushort4*)(dst + ((size_t)bh * SEQ + s) * HEAD_DIM + d0) = o;
            } else {
                unsigned short* vb = vtb + ((size_t)bh * HEAD_DIM + d0) * SEQV + s;
                vb[0]        = f2bf(v.x);
                vb[SEQV]     = f2bf(v.y);
                vb[2 * SEQV] = f2bf(v.z);
                vb[3 * SEQV] = f2bf(v.w);
            }
        }
    }
}

// ---------------------------------------------- out proj: out = attn @ W_o + b
__global__ __launch_bounds__(256) void out_mfma(
    const unsigned short* __restrict__ ab, const unsigned short* __restrict__ wt,
    const float* __restrict__ bias, float* __restrict__ out,
    int Mchunk, int row_off)
{
    __shared__ unsigned short Ws[128 * 32];
    __shared__ unsigned short Hs[128 * 32];
    int tid = threadIdx.x;
    int lane = tid & 63, wv = tid >> 6;
    int quad = lane >> 4, l15 = lane & 15;
    int wn = wv & 1, wm = wv >> 1;
    int n0 = blockIdx.x * 128;
    int m0 = blockIdx.y * 128;

    f32x4 acc[4][4];
    #pragma unroll
    for (int i = 0; i < 4; ++i)
        #pragma unroll
        for (int j = 0; j < 4; ++j) acc[i][j] = fzero();

    const unsigned short* wsrc = wt + (size_t)n0 * HIDDEN;
    const unsigned short* asrc = ab + (size_t)m0 * HIDDEN;

    for (int k0 = 0; k0 < HIDDEN; k0 += 32) {
        stage_tile(wsrc + k0, Ws, tid);
        stage_tile(asrc + k0, Hs, tid);
        __syncthreads();
        bf16x8 af[4], bfr[4];
        #pragma unroll
        for (int i = 0; i < 4; ++i) {
            int r = wn * 64 + i * 16 + l15;
            af[i] = *(const bf16x8*)(Ws + r * 32 + ((quad ^ ((r >> 1) & 3)) << 3));
        }
        #pragma unroll
        for (int j = 0; j < 4; ++j) {
            int r = wm * 64 + j * 16 + l15;
            bfr[j] = *(const bf16x8*)(Hs + r * 32 + ((quad ^ ((r >> 1) & 3)) << 3));
        }
        #pragma unroll
        for (int i = 0; i < 4; ++i)
            #pragma unroll
            for (int j = 0; j < 4; ++j)
                acc[i][j] = __builtin_amdgcn_mfma_f32_16x16x32_bf16(
                    af[i], bfr[j], acc[i][j], 0, 0, 0);
        __syncthreads();
    }

    #pragma unroll
    for (int j = 0; j < 4; ++j) {
        int m = m0 + wm * 64 + j * 16 + l15;
        if (m >= Mchunk) continue;
        size_t orow = (size_t)(row_off + m) * HIDDEN;
        #pragma unroll
        for (int i = 0; i < 4; ++i) {
            int nn = n0 + wn * 64 + i * 16 + quad * 4;
            f32x4 v = acc[i][j];
            const float4 bv = *(const float4*)(bias + nn);
            v.x += bv.x; v.y += bv.y; v.z += bv.z; v.w += bv.w;
            *(f32x4*)(out + orow + nn) = v;
        }
    }
}

// ------------------------------------------------- MFMA flash attention
// block: 128 queries x one (b,h); 4 waves x 32 queries; K-tiles of 64.
#define QT   128
#define KTT  64
#define KSTR 104   // Ks row stride (bf16): 2-way bank conflict max
#define VSTR 72    // Vt/Ps row stride
#define PSTR 72

__global__ __launch_bounds__(256, 3) void attn_mfma(
    const unsigned short* __restrict__ qb, const unsigned short* __restrict__ kb,
    const unsigned short* __restrict__ vtb, unsigned short* __restrict__ awsb)
{
    __shared__ unsigned short Ks[KTT * KSTR];   // 13.3 KB
    __shared__ unsigned short Vt[96 * VSTR];    // 13.8 KB
    __shared__ unsigned short Ps[QT * PSTR];    // 18.4 KB

    int tid = threadIdx.x;
    int lane = tid & 63, wv = tid >> 6;
    int quad = lane >> 4, l15 = lane & 15;
    int q0 = blockIdx.x * QT;
    int h = blockIdx.y, bb = blockIdx.z;
    int bh = bb * HEADS + h;
    const unsigned short* qg = qb  + (size_t)bh * SEQ * HEAD_DIM;
    const unsigned short* kg = kb  + (size_t)bh * SEQ * HEAD_DIM;
    const unsigned short* vg = vtb + (size_t)bh * HEAD_DIM * SEQV;

    // Q fragments in registers for the whole kernel (rows >= SEQ read pad; they
    // multiply zeroed K columns or are never stored).
    bf16x8 qf[2][3];
    #pragma unroll
    for (int mf = 0; mf < 2; ++mf)
        #pragma unroll
        for (int ks = 0; ks < 3; ++ks)
            qf[mf][ks] = *(const bf16x8*)(qg +
                (size_t)(q0 + wv * 32 + mf * 16 + l15) * HEAD_DIM + ks * 32 + quad * 8);

    f32x4 O[2][6];
    float m_i[2][4], l_i[2][4];
    #pragma unroll
    for (int mf = 0; mf < 2; ++mf) {
        #pragma unroll
        for (int nf = 0; nf < 6; ++nf) O[mf][nf] = fzero();
        #pragma unroll
        for (int r = 0; r < 4; ++r) { m_i[mf][r] = -INFINITY; l_i[mf][r] = 0.f; }
    }

    for (int k0 = 0; k0 < SEQ; k0 += KTT) {
        __syncthreads();
        // stage K tile: 64 rows x 96 cols (cols 88..95 zero)
        #pragma unroll
        for (int it = 0; it < 3; ++it) {
            int idx = it * 256 + tid;          // 0..767
            int r = idx / 12, c = idx - r * 12;
            bf16x8 v = (bf16x8)(short)0;
            if (c < 11)
                v = *(const bf16x8*)(kg + (size_t)(k0 + r) * HEAD_DIM + c * 8);
            *(bf16x8*)(Ks + r * KSTR + c * 8) = v;
        }
        // stage V^T tile: 96 rows (d) x 64 cols (keys)
        #pragma unroll
        for (int it = 0; it < 3; ++it) {
            int idx = it * 256 + tid;          // 0..767
            int r = idx >> 3, c = idx & 7;
            bf16x8 v = *(const bf16x8*)(vg + (size_t)r * SEQV + k0 + c * 8);
            *(bf16x8*)(Vt + r * VSTR + c * 8) = v;
        }
        __syncthreads();

        // QK^T: rows=queries, cols=keys
        f32x4 sc[2][4];
        #pragma unroll
        for (int mf = 0; mf < 2; ++mf)
            #pragma unroll
            for (int nf = 0; nf < 4; ++nf) sc[mf][nf] = fzero();
        #pragma unroll
        for (int ks = 0; ks < 3; ++ks) {
            #pragma unroll
            for (int nf = 0; nf < 4; ++nf) {
                bf16x8 b = *(const bf16x8*)(Ks + (nf * 16 + l15) * KSTR + ks * 32 + quad * 8);
                sc[0][nf] = __builtin_amdgcn_mfma_f32_16x16x32_bf16(qf[0][ks], b, sc[0][nf], 0, 0, 0);
                sc[1][nf] = __builtin_amdgcn_mfma_f32_16x16x32_bf16(qf[1][ks], b, sc[1][nf], 0, 0, 0);
            }
        }

        // online softmax (row = quad*4+reg; per-row state replicated over l15)
        #pragma unroll
        for (int mf = 0; mf < 2; ++mf) {
            float mx[4];
            #pragma unroll
            for (int r = 0; r < 4; ++r) {
                float v = -INFINITY;
                #pragma unroll
                for (int nf = 0; nf < 4; ++nf)
                    if (k0 + nf * 16 + l15 < SEQ) v = fmaxf(v, sc[mf][nf][r]);
                #pragma unroll
                for (int off = 8; off; off >>= 1)
                    v = fmaxf(v, __shfl_xor(v, off, 16));
                mx[r] = v;
            }
            #pragma unroll
            for (int r = 0; r < 4; ++r) {
                float mnew  = fmaxf(m_i[mf][r], mx[r]);
                float alpha = __expf(m_i[mf][r] - mnew);
                m_i[mf][r] = mnew;
                float rsum = 0.f;
                #pragma unroll
                for (int nf = 0; nf < 4; ++nf) {
                    bool valid = (k0 + nf * 16 + l15 < SEQ);
                    float p = valid ? __expf(sc[mf][nf][r] - mnew) : 0.f;
                    sc[mf][nf][r] = p;
                    rsum += p;
                }
                #pragma unroll
                for (int off = 8; off; off >>= 1)
                    rsum += __shfl_xor(rsum, off, 16);
                l_i[mf][r] = l_i[mf][r] * alpha + rsum;
                #pragma unroll
                for (int nf = 0; nf < 6; ++nf) O[mf][nf][r] *= alpha;
            }
            // P -> LDS (wave-private rows; no barrier needed)
            #pragma unroll
            for (int nf = 0; nf < 4; ++nf)
                #pragma unroll
                for (int r = 0; r < 4; ++r)
                    Ps[(wv * 32 + mf * 16 + quad * 4 + r) * PSTR + nf * 16 + l15] =
                        f2bf(sc[mf][nf][r]);
        }

        // PV: rows=queries, cols=d
        #pragma unroll
        for (int ks = 0; ks < 2; ++ks) {
            bf16x8 a0 = *(const bf16x8*)(Ps + (wv * 32 + l15) * PSTR + ks * 32 + quad * 8);
            bf16x8 a1 = *(const bf16x8*)(Ps + (wv * 32 + 16 + l15) * PSTR + ks * 32 + quad * 8);
            #pragma unroll
            for (int nf = 0; nf < 6; ++nf) {
                bf16x8 b = *(const bf16x8*)(Vt + (nf * 16 + l15) * VSTR + ks * 32 + quad * 8);
                O[0][nf] = __builtin_amdgcn_mfma_f32_16x16x32_bf16(a0, b, O[0][nf], 0, 0, 0);
                O[1][nf] = __builtin_amdgcn_mfma_f32_16x16x32_bf16(a1, b, O[1][nf], 0, 0, 0);
            }
        }
    }

    // epilogue
    #pragma unroll
    for (int mf = 0; mf < 2; ++mf) {
        #pragma unroll
        for (int r = 0; r < 4; ++r) {
            int row = q0 + wv * 32 + mf * 16 + quad * 4 + r;
            if (row >= SEQ) continue;
            float il = 1.f / l_i[mf][r];
            size_t base = (size_t)(bb * SEQ + row) * HIDDEN + h * HEAD_DIM;
            #pragma unroll
            for (int nf = 0; nf < 6; ++nf) {
                int d = nf * 16 + l15;
                if (d < HEAD_DIM)
                    awsb[base + d] = f2bf(O[mf][nf][r] * il);
            }
        }
    }
}

// ---------------------------------------------------------------- launcher
extern "C" void kernel_launch(void* const* d_in, const int* in_sizes, int n_in,
                              void* d_out, int out_size, void* d_ws, size_t ws_size,
                              hipStream_t stream) {
    const float* hs    = (const float*)d_in[0];
    const float* w_qkv = (const float*)d_in[1];
    const float* b_qkv = (const float*)d_in[2];
    const float* w_o   = (const float*)d_in[3];
    const float* b_o   = (const float*)d_in[4];
    float* out = (float*)d_out;

    char* p = (char*)d_ws;
    auto alloc = [&](size_t bytes) {
        char* r = p; p += (bytes + 255) & ~(size_t)255; return r;
    };
    float*          cosb   = (float*)alloc((size_t)SEQ * RD * 4);
    float*          sinb   = (float*)alloc((size_t)SEQ * RD * 4);
    unsigned short* wqkv_t = (unsigned short*)alloc((size_t)NQKV * HIDDEN * 2);
    unsigned short* wo_t   = (unsigned short*)alloc((size_t)HIDDEN * HIDDEN * 2);
    unsigned short* hs_bf  = (unsigned short*)alloc((size_t)MPAD_ROWS * HIDDEN * 2);
    size_t fixed = (size_t)(p - (char*)d_ws);

    // per-batch: q + k ([16][577][88] bf16) + vt ([16][88][640] bf16) + attn rows
    size_t per_batch = 2ull * HEADS * SEQ * HEAD_DIM * 2
                     + (size_t)HEADS * HEAD_DIM * SEQV * 2
                     + (size_t)SEQ * HIDDEN * 2;
    size_t pads = 2ull * 64 * HEAD_DIM * 2 + 16ull * SEQV * 2 + 128ull * HIDDEN * 2 + 16 * 256;
    size_t rem = (ws_size > fixed + pads) ? ws_size - fixed - pads : 0;
    int CB = (int)(rem / per_batch);
    if (CB < 1) CB = 1;
    if (CB > 32) CB = 32;

    unsigned short* qbuf = (unsigned short*)alloc(((size_t)CB * HEADS * SEQ + 64) * HEAD_DIM * 2);
    unsigned short* kbuf = (unsigned short*)alloc(((size_t)CB * HEADS * SEQ + 64) * HEAD_DIM * 2);
    unsigned short* vtbuf = (unsigned short*)alloc(((size_t)CB * HEADS * HEAD_DIM + 16) * SEQV * 2);
    unsigned short* awsb = (unsigned short*)alloc(((size_t)CB * SEQ + 128) * HIDDEN * 2);

    rope_precompute<<<dim3(SEQ), dim3(64), 0, stream>>>(cosb, sinb);

    long nreal = (long)32 * SEQ * HIDDEN;
    long ntot  = (long)MPAD_ROWS * HIDDEN;
    conv_hs<<<dim3((unsigned)((ntot / 4 + 255) / 256)), 256, 0, stream>>>(hs, hs_bf, nreal, ntot);
    conv_wT<<<dim3(NQKV / 32, HIDDEN / 32), 256, 0, stream>>>(w_qkv, wqkv_t, HIDDEN, NQKV);
    conv_wT<<<dim3(HIDDEN / 32, HIDDEN / 32), 256, 0, stream>>>(w_o, wo_t, HIDDEN, HIDDEN);

    for (int b_off = 0; b_off < 32; b_off += CB) {
        int nb = (32 - b_off < CB) ? (32 - b_off) : CB;
        int M = nb * SEQ;

        dim3 g1(NQKV / 128, (M + 127) / 128);
        qkv_mfma<<<g1, 256, 0, stream>>>(hs_bf, wqkv_t, b_qkv, cosb, sinb,
                                         qbuf, kbuf, vtbuf, M, b_off * SEQ);
        dim3 g2((SEQ + QT - 1) / QT, HEADS, nb);
        attn_mfma<<<g2, 256, 0, stream>>>(qbuf, kbuf, vtbuf, awsb);
        dim3 g3(HIDDEN / 128, (M + 127) / 128);
        out_mfma<<<g3, 256, 0, stream>>>(awsb, wo_t, b_o, out, M, b_off * SEQ);
    }
}